// Round 10
// baseline (3809.578 us; speedup 1.0000x reference)
//
#include <hip/hip_runtime.h>
#include <hip/hip_bf16.h>
#include <math.h>

// Seq2seq GRU (r,z,n), H=1024, L=2, S=T=512, V=32000.
// Round 10: XCD-local chains, spill-free (r7 retried with correct VGPR budget).
//  gru_persist: 256 WGs x 512 thr, __launch_bounds__(512,1) -> <=256 VGPR,
//  1 WG/CU capacity-forced (wreg 192 VGPR), 32 WGs/XCD. Slot claim via
//  XCC_ID + per-XCD rank; displaced WGs CAS-scan a 256-slot bitmap (complete
//  coverage even under XCC_ID pathology).
//   slots   0- 31: L0 chain (XCD0): 32 elem/WG, Whh-only (96 rows, 12/wave),
//                  gi polled from GI0; h self-recurrence intra-XCD.
//   slots  32- 63: L1 chain (XCD1): same, gi from GI1 (helpers).
//   slots  64-127: helpers (XCD2-3): gi1[t] = Wih^L1 @ h^L0[t] + bih^L1
//                  (cross-XCD poll of h^L0 -> constant lag, not rate).
//   slots 128-255: producers (XCD4-7): GI0[p][t] = Wih^L0 @ x[t] + bih^L0
//                  (static x, race ahead of the chain).
//  Chain step: sliced 2-pair poll -> LDS dbuf -> 1 barrier -> 12 dots ->
//  butterfly -> in-wave gates (static sel4) -> tagged publish. All spins
//  bounded -> NaN (visible failure, never a hang).
// Then: gemm_mfma (A=D1b bf16, B=out_W f32 cast inline) + log-softmax.

#define HID 1024
#define NSTEP 512
#define VOCAB 32000
#define SPIN_LIMIT 50000
typedef unsigned long long u64;
typedef unsigned int u32;

__device__ __forceinline__ u64 ald(const u64* p) {
    return __hip_atomic_load((u64*)p, __ATOMIC_RELAXED, __HIP_MEMORY_SCOPE_AGENT);
}
__device__ __forceinline__ void ast(u64* p, u64 v) {
    __hip_atomic_store(p, v, __ATOMIC_RELAXED, __HIP_MEMORY_SCOPE_AGENT);
}
__device__ __forceinline__ u64 pack_hv(float v, u32 tag) {
    return ((u64)tag << 32) | (u64)__float_as_uint(v);
}
__device__ __forceinline__ float payload(u64 v) {
    return __uint_as_float((u32)(v & 0xffffffffu));
}
__device__ __forceinline__ u32 bf16_rtne(float f) {
    u32 x = __float_as_uint(f);
    return (x + 0x7fffu + ((x >> 16) & 1u)) >> 16;
}
__device__ __forceinline__ float sel4(float a, float b, float c, float d, int j) {
    float ab = (j & 1) ? b : a;
    float cd = (j & 1) ? d : c;
    return (j & 2) ? cd : ab;
}
__device__ __forceinline__ float sel6(float a, float b, float c, float d, float e,
                                      float f, int j) {
    float s01 = (j & 1) ? b : a;
    float s23 = (j & 1) ? d : c;
    float s45 = (j & 1) ? f : e;
    float s03 = (j & 2) ? s23 : s01;
    return (j & 4) ? s45 : s03;
}
__device__ __forceinline__ u32 gi_tag(int p, int t) {
    return 0x40000000u | ((u32)p << 16) | (u32)t;
}

// ---------------------------------------------------------------- embeddings
__global__ __launch_bounds__(256) void gather_embed(
    const int* __restrict__ src_tok, const int* __restrict__ tgt_tok,
    const float* __restrict__ src_emb, const float* __restrict__ tgt_emb,
    float* __restrict__ enc_x, float* __restrict__ dec_x) {
    int b = blockIdx.x, tid = threadIdx.x;
    int tok;
    const float* src;
    float* dst;
    if (b < 512) {
        tok = src_tok[b];
        src = src_emb;
        dst = enc_x + (size_t)b * HID;
    } else {
        int t = b - 512;
        tok = (t == 0) ? 0 : tgt_tok[t - 1];  // BOS = 0
        src = tgt_emb;
        dst = dec_x + (size_t)t * HID;
    }
    float4 v = *(const float4*)(src + (size_t)tok * HID + tid * 4);
    *(float4*)(dst + tid * 4) = v;
}

// ---------------------------------------------------------------- recurrence
__global__ __launch_bounds__(512, 1) void gru_persist(
    const float* __restrict__ enc_x, const float* __restrict__ dec_x,
    const float* __restrict__ eWih, const float* __restrict__ eWhh,
    const float* __restrict__ eBih, const float* __restrict__ eBhh,
    const float* __restrict__ dWih, const float* __restrict__ dWhh,
    const float* __restrict__ dBih, const float* __restrict__ dBhh,
    u64* H0, u64* H1, u64* D0, u64* D1, u64* GI0, u64* GI1,
    unsigned short* __restrict__ D1b, u32* cnt, u32* slots) {
    const int tid = threadIdx.x;
    const int wave = tid >> 6, lane = tid & 63;

    __shared__ int s_slot;
    __shared__ __align__(16) float xbuf[2][HID];

    if (tid == 0) {
        u32 xcc = (u32)__builtin_amdgcn_s_getreg((31u << 11) | 20u) & 7u;
        u32 k = atomicAdd(&cnt[xcc], 1u);
        int s = -1;
        if (k < 32u) {
            s = (int)(xcc * 32u + k);
            if (atomicExch(&slots[s], 1u) != 0u) s = -1;  // stolen by a scanner
        }
        for (int pass = 0; s < 0 && pass < 64; ++pass)
            for (int i = 0; i < 256 && s < 0; ++i)
                if (atomicCAS(&slots[i], 0u, 1u) == 0u) s = i;
        s_slot = s;
    }
    __syncthreads();
    const int s = s_slot;
    if (s < 0) return;

    if (s < 64) {
        // ================= chain (role = layer), 32 elements, Whh only ======
        const int role = s >> 5;           // 0: L0 (XCD0), 1: L1 (XCD1)
        const int rs = s & 31;
        const int j0 = rs * 32;
        const int je = j0 + wave * 4 + (lane & 3);
        float wreg[12][16];
        float hprev = 0.f;

#pragma unroll 1
        for (int p = 0; p < 2; ++p) {
            const float* Whh = (p ? dWhh : eWhh) + (size_t)role * 3 * HID * HID;
            const float* bhh = (p ? dBhh : eBhh) + (size_t)role * 3 * HID;
            u64* hch = p ? (role ? D1 : D0) : (role ? H1 : H0);
            const u32 tagOut = p ? (role ? 4u : 3u) : (role ? 2u : 1u);
            u64* prevch = role ? H1 : H0;
            const u32 tagPrev = role ? 2u : 1u;
            const u64* gsrc = (role ? GI1 : GI0) + (size_t)p * NSTEP * 3 * HID;

            __syncthreads();  // xbuf/phase reuse guard
            // rows: r = g*4+e -> Whh[g*HID + j0 + wave*4 + e]
#pragma unroll
            for (int g = 0; g < 3; ++g)
#pragma unroll
                for (int e = 0; e < 4; ++e) {
                    const float* base =
                        Whh + (size_t)(g * HID + j0 + wave * 4 + e) * HID;
#pragma unroll
                    for (int q = 0; q < 16; ++q)
                        wreg[g * 4 + e][q] = base[q * 64 + lane];
                }
            float bR = 0.f, bZ = 0.f, bN = 0.f;
            if ((lane & 63) < 4) {
                bR = bhh[je];
                bZ = bhh[HID + je];
                bN = bhh[2 * HID + je];
            }
            __syncthreads();

#pragma unroll 1
            for (int t = 0; t < NSTEP; ++t) {
                float* xb = xbuf[t & 1];
                // early gi loads (verified at use)
                u64 g0 = 0, g1 = 0, g2 = 0;
                const u64* gp = gsrc + (size_t)t * 3 * HID + je;
                const u32 wantGI = gi_tag(p, t);
                if (lane < 4) {
                    g0 = ald(gp);
                    g1 = ald(gp + HID);
                    g2 = ald(gp + 2 * HID);
                }
                // own-chain h_{t-1}: sliced poll (wave covers q = 2w, 2w+1)
                {
                    const int qa = 2 * wave, qb = qa + 1;
                    if (t == 0 && p == 0) {
                        xb[qa * 64 + lane] = 0.f;
                        xb[qb * 64 + lane] = 0.f;
                    } else {
                        const u64* srcp = (t > 0)
                                              ? hch + (size_t)(t - 1) * HID
                                              : prevch + (size_t)(NSTEP - 1) * HID;
                        const u32 want = (t > 0) ? tagOut : tagPrev;
                        const u64* pa = srcp + qa * 64 + lane;
                        const u64* pb = srcp + qb * 64 + lane;
                        u64 va, vb;
                        int it = 0;
                        for (;;) {
                            va = ald(pa);
                            vb = ald(pb);
                            if ((u32)(va >> 32) == want && (u32)(vb >> 32) == want)
                                break;
                            if (++it >= SPIN_LIMIT) {
                                va = vb = 0x7fc00000ull;
                                break;
                            }
                        }
                        xb[qa * 64 + lane] = payload(va);
                        xb[qb * 64 + lane] = payload(vb);
                    }
                }
                __syncthreads();

                float part[12] = {0.f, 0.f, 0.f, 0.f, 0.f, 0.f,
                                  0.f, 0.f, 0.f, 0.f, 0.f, 0.f};
#pragma unroll
                for (int q = 0; q < 16; ++q) {
                    float vq = xb[q * 64 + lane];
#pragma unroll
                    for (int r = 0; r < 12; ++r)
                        part[r] = fmaf(wreg[r][q], vq, part[r]);
                }
#pragma unroll
                for (int off = 1; off < 64; off <<= 1)
#pragma unroll
                    for (int r = 0; r < 12; ++r)
                        part[r] += __shfl_xor(part[r], off);

                if (lane < 4) {
                    const int e = lane;
                    float hr = sel4(part[0], part[1], part[2], part[3], e) + bR;
                    float hz = sel4(part[4], part[5], part[6], part[7], e) + bZ;
                    float hn = sel4(part[8], part[9], part[10], part[11], e) + bN;
                    int it = 0;
                    while ((u32)(g0 >> 32) != wantGI || (u32)(g1 >> 32) != wantGI ||
                           (u32)(g2 >> 32) != wantGI) {
                        if (++it >= SPIN_LIMIT) {
                            g0 = g1 = g2 = 0x7fc00000ull;
                            break;
                        }
                        g0 = ald(gp);
                        g1 = ald(gp + HID);
                        g2 = ald(gp + 2 * HID);
                    }
                    float rg = 1.f / (1.f + __expf(-(payload(g0) + hr)));
                    float zg = 1.f / (1.f + __expf(-(payload(g1) + hz)));
                    float na = payload(g2) + rg * hn;
                    float ng = 2.f / (1.f + __expf(-2.f * na)) - 1.f;  // tanh
                    float hnew = (1.f - zg) * ng + zg * hprev;
                    hprev = hnew;
                    ast(hch + (size_t)t * HID + je, pack_hv(hnew, tagOut));
                    if (p == 1 && role == 1)
                        D1b[(size_t)t * HID + je] = (unsigned short)bf16_rtne(hnew);
                }
            }
        }
    } else if (s < 128) {
        // ================= helper: gi1 = Wih^L1 @ h^L0 + bih^L1 =============
        const int rs = s - 64;
        const int m0 = rs * 48;  // 48 of 3072 flat rows
        float wr6[6][16];
#pragma unroll 1
        for (int p = 0; p < 2; ++p) {
            const float* Wih1 = (p ? dWih : eWih) + (size_t)3 * HID * HID;  // layer1
            const float* bih1 = (p ? dBih : eBih) + 3 * HID;
            const u64* srcc = p ? D0 : H0;
            const u32 wantH = p ? 3u : 1u;
            u64* gout = GI1 + (size_t)p * NSTEP * 3 * HID;

            __syncthreads();
#pragma unroll
            for (int r = 0; r < 6; ++r) {
                const float* base = Wih1 + (size_t)(m0 + wave * 6 + r) * HID;
#pragma unroll
                for (int q = 0; q < 16; ++q) wr6[r][q] = base[q * 64 + lane];
            }
            float bi = 0.f;
            if (lane < 6) bi = bih1[m0 + wave * 6 + lane];
            __syncthreads();

#pragma unroll 1
            for (int t = 0; t < NSTEP; ++t) {
                float* xb = xbuf[t & 1];
                const int qa = 2 * wave, qb = qa + 1;
                const u64* pa = srcc + (size_t)t * HID + qa * 64 + lane;
                const u64* pb = srcc + (size_t)t * HID + qb * 64 + lane;
                u64 va, vb;
                int it = 0;
                for (;;) {
                    va = ald(pa);
                    vb = ald(pb);
                    if ((u32)(va >> 32) == wantH && (u32)(vb >> 32) == wantH) break;
                    if (++it >= SPIN_LIMIT) {
                        va = vb = 0x7fc00000ull;
                        break;
                    }
                    __builtin_amdgcn_s_sleep(4);  // throttle cross-XCD poll storm
                }
                xb[qa * 64 + lane] = payload(va);
                xb[qb * 64 + lane] = payload(vb);
                __syncthreads();

                float part[6] = {0.f, 0.f, 0.f, 0.f, 0.f, 0.f};
#pragma unroll
                for (int q = 0; q < 16; ++q) {
                    float vq = xb[q * 64 + lane];
#pragma unroll
                    for (int r = 0; r < 6; ++r)
                        part[r] = fmaf(wr6[r][q], vq, part[r]);
                }
#pragma unroll
                for (int off = 1; off < 64; off <<= 1)
#pragma unroll
                    for (int r = 0; r < 6; ++r)
                        part[r] += __shfl_xor(part[r], off);
                if (lane < 6) {
                    float val = sel6(part[0], part[1], part[2], part[3], part[4],
                                     part[5], lane) + bi;
                    ast(gout + (size_t)t * 3 * HID + m0 + wave * 6 + lane,
                        pack_hv(val, gi_tag(p, t)));
                }
            }
        }
    } else {
        // ================= producer: GI0[p] = Wih^L0 @ x + bih^L0 ===========
        const int p = (s < 192) ? 0 : 1;
        const int rs = (s - 128) & 63;
        const int m0 = rs * 48;
        const float* Wih0 = p ? dWih : eWih;  // layer0
        const float* bih0 = p ? dBih : eBih;
        const float* xs = p ? dec_x : enc_x;
        u64* gout = GI0 + (size_t)p * NSTEP * 3 * HID;
        float wr6[6][16];
#pragma unroll
        for (int r = 0; r < 6; ++r) {
            const float* base = Wih0 + (size_t)(m0 + wave * 6 + r) * HID;
#pragma unroll
            for (int q = 0; q < 16; ++q) wr6[r][q] = base[q * 64 + lane];
        }
        float bi = 0.f;
        if (lane < 6) bi = bih0[m0 + wave * 6 + lane];

#pragma unroll 1
        for (int t = 0; t < NSTEP; ++t) {
            const float* xr = xs + (size_t)t * HID;
            float part[6] = {0.f, 0.f, 0.f, 0.f, 0.f, 0.f};
#pragma unroll
            for (int q = 0; q < 16; ++q) {
                float vq = xr[q * 64 + lane];
#pragma unroll
                for (int r = 0; r < 6; ++r) part[r] = fmaf(wr6[r][q], vq, part[r]);
            }
#pragma unroll
            for (int off = 1; off < 64; off <<= 1)
#pragma unroll
                for (int r = 0; r < 6; ++r) part[r] += __shfl_xor(part[r], off);
            if (lane < 6) {
                float val = sel6(part[0], part[1], part[2], part[3], part[4],
                                 part[5], lane) + bi;
                ast(gout + (size_t)t * 3 * HID + m0 + wave * 6 + lane,
                    pack_hv(val, gi_tag(p, t)));
            }
        }
    }
}

// ---------------------------------------------------------------- MFMA GEMM
// C[i][v] = sum_k A[i][k]*B[v][k] + bias[v]; A bf16, B f32 (cast inline), C f32.
__global__ __launch_bounds__(256) void gemm_mfma(
    const unsigned short* __restrict__ A, const float* __restrict__ B,
    const float* __restrict__ bias, float* __restrict__ C) {
    typedef __attribute__((ext_vector_type(8))) short short8;
    typedef __attribute__((ext_vector_type(4))) float f32x4;
    const int lane = threadIdx.x & 63, wave = threadIdx.x >> 6;
    const int i0 = blockIdx.x * 64;
    const int v0 = blockIdx.y * 256 + wave * 64;
    const int r16 = lane & 15, kq = lane >> 4;

    f32x4 acc[4][4] = {};
#pragma unroll 4
    for (int k0 = 0; k0 < HID; k0 += 32) {
        short8 a[4], b[4];
#pragma unroll
        for (int mf = 0; mf < 4; ++mf)
            a[mf] = *(const short8*)(A + (size_t)(i0 + mf * 16 + r16) * HID + k0 +
                                     kq * 8);
#pragma unroll
        for (int nf = 0; nf < 4; ++nf) {
            const float* wp = B + (size_t)(v0 + nf * 16 + r16) * HID + k0 + kq * 8;
            float4 w0 = *(const float4*)wp;
            float4 w1 = *(const float4*)(wp + 4);
            short8 bb;
            bb[0] = (short)bf16_rtne(w0.x);
            bb[1] = (short)bf16_rtne(w0.y);
            bb[2] = (short)bf16_rtne(w0.z);
            bb[3] = (short)bf16_rtne(w0.w);
            bb[4] = (short)bf16_rtne(w1.x);
            bb[5] = (short)bf16_rtne(w1.y);
            bb[6] = (short)bf16_rtne(w1.z);
            bb[7] = (short)bf16_rtne(w1.w);
            b[nf] = bb;
        }
#pragma unroll
        for (int mf = 0; mf < 4; ++mf)
#pragma unroll
            for (int nf = 0; nf < 4; ++nf)
                acc[mf][nf] = __builtin_amdgcn_mfma_f32_16x16x32_bf16(
                    a[mf], b[nf], acc[mf][nf], 0, 0, 0);
    }
#pragma unroll
    for (int nf = 0; nf < 4; ++nf) {
        float bb = bias[v0 + nf * 16 + r16];
#pragma unroll
        for (int mf = 0; mf < 4; ++mf)
#pragma unroll
            for (int reg = 0; reg < 4; ++reg) {
                int i = i0 + mf * 16 + kq * 4 + reg;
                C[(size_t)i * VOCAB + v0 + nf * 16 + r16] = acc[mf][nf][reg] + bb;
            }
    }
}

// ---------------------------------------------------------------- log-softmax
__global__ __launch_bounds__(256) void log_softmax_inplace(float* __restrict__ C) {
    const int row = blockIdx.x;
    const int tid = threadIdx.x;
    float* p = C + (size_t)row * VOCAB;
    float m = -3.4e38f, s = 0.f;
    for (int idx = tid; idx < VOCAB / 4; idx += 256) {
        float4 x = ((const float4*)p)[idx];
        float xv[4] = {x.x, x.y, x.z, x.w};
#pragma unroll
        for (int u = 0; u < 4; u++) {
            float nm = fmaxf(m, xv[u]);
            s = s * __expf(m - nm) + __expf(xv[u] - nm);
            m = nm;
        }
    }
#pragma unroll
    for (int off = 1; off < 64; off <<= 1) {
        float om = __shfl_xor(m, off);
        float os = __shfl_xor(s, off);
        float nm = fmaxf(m, om);
        s = s * __expf(m - nm) + os * __expf(om - nm);
        m = nm;
    }
    __shared__ float sm[4], ss[4], sL;
    int wv = tid >> 6;
    if ((tid & 63) == 0) { sm[wv] = m; ss[wv] = s; }
    __syncthreads();
    if (tid == 0) {
        float M = sm[0], S = ss[0];
        for (int w = 1; w < 4; w++) {
            float nm = fmaxf(M, sm[w]);
            S = S * __expf(M - nm) + ss[w] * __expf(sm[w] - nm);
            M = nm;
        }
        sL = M + logf(S);
    }
    __syncthreads();
    float L = sL;
    for (int idx = tid; idx < VOCAB / 4; idx += 256) {
        float4 x = ((const float4*)p)[idx];
        x.x -= L; x.y -= L; x.z -= L; x.w -= L;
        ((float4*)p)[idx] = x;
    }
}

// ---------------------------------------------------------------- launcher
extern "C" void kernel_launch(void* const* d_in, const int* in_sizes, int n_in,
                              void* d_out, int out_size, void* d_ws, size_t ws_size,
                              hipStream_t stream) {
    const int* src_tok = (const int*)d_in[0];
    const int* tgt_tok = (const int*)d_in[1];
    const float* src_emb = (const float*)d_in[2];
    const float* tgt_emb = (const float*)d_in[3];
    const float* eWih = (const float*)d_in[4];
    const float* eWhh = (const float*)d_in[5];
    const float* eBih = (const float*)d_in[6];
    const float* eBhh = (const float*)d_in[7];
    const float* dWih = (const float*)d_in[8];
    const float* dWhh = (const float*)d_in[9];
    const float* dBih = (const float*)d_in[10];
    const float* dBhh = (const float*)d_in[11];
    const float* out_W = (const float*)d_in[12];
    const float* out_b = (const float*)d_in[13];
    float* out = (float*)d_out;

    char* ws = (char*)d_ws;
    // layout (MiB): enc_x 0-2 | dec_x 2-4 | H0 4-8 | H1 8-12 | D0 12-16 |
    //   D1 16-20 | D1b 20-21 | cnt/slots 21-22 | GI0 22-46 | GI1 46-70
    // (ws_size >= 87 MiB empirically established in round 9.)
    float* enc_x = (float*)(ws);
    float* dec_x = (float*)(ws + (2ull << 20));
    u64* H0 = (u64*)(ws + (4ull << 20));
    u64* H1 = (u64*)(ws + (8ull << 20));
    u64* D0 = (u64*)(ws + (12ull << 20));
    u64* D1 = (u64*)(ws + (16ull << 20));
    unsigned short* D1b = (unsigned short*)(ws + (20ull << 20));
    u32* cnt = (u32*)(ws + (21ull << 20));
    u32* slots = cnt + 16;
    u64* GI0 = (u64*)(ws + (22ull << 20));
    u64* GI1 = (u64*)(ws + (46ull << 20));

    // Zero all tagged buffers + claim state every launch.
    hipMemsetAsync(ws + (4ull << 20), 0, 66ull << 20, stream);

    gather_embed<<<1024, 256, 0, stream>>>(src_tok, tgt_tok, src_emb, tgt_emb,
                                           enc_x, dec_x);
    gru_persist<<<256, 512, 0, stream>>>(enc_x, dec_x, eWih, eWhh, eBih, eBhh,
                                         dWih, dWhh, dBih, dBhh, H0, H1, D0, D1,
                                         GI0, GI1, D1b, cnt, slots);
    gemm_mfma<<<dim3(8, 125), 256, 0, stream>>>(D1b, out_W, out_b, out);
    log_softmax_inplace<<<512, 256, 0, stream>>>(out);
}

// Round 11
// 3470.038 us; speedup vs baseline: 1.0978x; 1.0978x over previous
//
#include <hip/hip_runtime.h>
#include <hip/hip_bf16.h>
#include <math.h>

// Seq2seq GRU (r,z,n), H=1024, L=2, S=T=512, V=32000.
// Round 11: EXACT r9 kernel (best total, 3487us) with ONE change:
//   the tagged h-publish uses a fire-and-forget agent-scope atomic EXCHANGE
//   (global_atomic_swap, no-return) instead of a relaxed atomic store.
//   Rationale: RMW atomics execute at the device coherence point and are not
//   write-combine-buffered -> tests whether store-drain latency is the ~2us
//   hidden term in the 3.3us/hop sync constant.
// Everything else (r4 recurrence structure, bf16-MFMA output GEMM with
// ws-gated fallback, log-softmax) is byte-identical to round 9.

#define HID 1024
#define NSTEP 512
#define VOCAB 32000
#define SPIN_LIMIT 50000
typedef unsigned long long u64;
typedef unsigned int u32;

__device__ __forceinline__ u64 pack_hv(float v, u32 tag) {
    return ((u64)tag << 32) | (u64)__float_as_uint(v);
}
__device__ __forceinline__ u32 bf16_rtne(float f) {
    u32 x = __float_as_uint(f);
    return (x + 0x7fffu + ((x >> 16) & 1u)) >> 16;
}
// Publish: fire-and-forget atomic swap (no-return form -> no producer stall).
__device__ __forceinline__ void publish(u64* p, u64 v) {
    (void)__hip_atomic_exchange(p, v, __ATOMIC_RELAXED, __HIP_MEMORY_SCOPE_AGENT);
}

// Per-lane: poll 16 tagged pairs row[q*64+lane] until all tags == want; payloads
// into v[16]. Bounded: on give-up fill NaN (diagnostic channel).
__device__ __forceinline__ void poll16(const u64* __restrict__ row, u32 want,
                                       float* v, int lane) {
    u64 p[16];
    int iter = 0;
    for (;;) {
        bool ok = true;
#pragma unroll
        for (int q = 0; q < 16; ++q) {
            p[q] = __hip_atomic_load((u64*)(row + q * 64 + lane),
                                     __ATOMIC_RELAXED, __HIP_MEMORY_SCOPE_AGENT);
            ok = ok && ((u32)(p[q] >> 32) == want);
        }
        if (ok) break;
        if (++iter >= SPIN_LIMIT) {
#pragma unroll
            for (int q = 0; q < 16; ++q) v[q] = __uint_as_float(0x7fc00000u);
            return;
        }
        __builtin_amdgcn_s_sleep(1);
    }
#pragma unroll
    for (int q = 0; q < 16; ++q)
        v[q] = __uint_as_float((u32)(p[q] & 0xffffffffu));
}

// ---------------------------------------------------------------- embeddings
__global__ __launch_bounds__(256) void gather_embed(
    const int* __restrict__ src_tok, const int* __restrict__ tgt_tok,
    const float* __restrict__ src_emb, const float* __restrict__ tgt_emb,
    float* __restrict__ enc_x, float* __restrict__ dec_x) {
    int b = blockIdx.x, tid = threadIdx.x;
    int tok;
    const float* src;
    float* dst;
    if (b < 512) {
        tok = src_tok[b];
        src = src_emb;
        dst = enc_x + (size_t)b * HID;
    } else {
        int t = b - 512;
        tok = (t == 0) ? 0 : tgt_tok[t - 1];  // BOS = 0
        src = tgt_emb;
        dst = dec_x + (size_t)t * HID;
    }
    float4 v = *(const float4*)(src + (size_t)tok * HID + tid * 4);
    *(float4*)(dst + tid * 4) = v;
}

// ---------------------------------------------------------------- f32 -> bf16
__global__ __launch_bounds__(256) void cast_w(const float* __restrict__ W,
                                              unsigned short* __restrict__ Wb) {
    size_t base = ((size_t)blockIdx.x * 256 + threadIdx.x) * 8;
    const float4* s = (const float4*)(W + base);
    float4 f0 = s[0], f1 = s[1];
    uint4 o;
    o.x = bf16_rtne(f0.x) | (bf16_rtne(f0.y) << 16);
    o.y = bf16_rtne(f0.z) | (bf16_rtne(f0.w) << 16);
    o.z = bf16_rtne(f1.x) | (bf16_rtne(f1.y) << 16);
    o.w = bf16_rtne(f1.z) | (bf16_rtne(f1.w) << 16);
    *(uint4*)(Wb + base) = o;
}

// ---------------------------------------------------------------- recurrence
// r4 structure verbatim: 256 WGs x 256 thr; role = bid>>7; WG owns 8 elements.
// Waves 0-1: Wih rows vs x; waves 2-3: Whh rows vs h. Gates on tid<8.
__global__ __launch_bounds__(256, 1) void gru_persist(
    const float* __restrict__ enc_x, const float* __restrict__ dec_x,
    const float* __restrict__ eWih, const float* __restrict__ eWhh,
    const float* __restrict__ eBih, const float* __restrict__ eBhh,
    const float* __restrict__ dWih, const float* __restrict__ dWhh,
    const float* __restrict__ dBih, const float* __restrict__ dBhh,
    u64* H0, u64* H1, u64* D0, u64* D1, float* __restrict__ D1f,
    unsigned short* __restrict__ D1b) {
    const int tid = threadIdx.x;
    const int wave = tid >> 6, lane = tid & 63;
    const int role = blockIdx.x >> 7;
    const int wl = blockIdx.x & 127;
    const int j0 = wl * 8;

    __shared__ float dots[48];
    __shared__ float sbias[48];

    float wreg[12][16];
    float hprev = 0.f;

#pragma unroll 1
    for (int phase = 0; phase < 2; ++phase) {
        const bool dec = (phase == 1);
        const float* Wih = (dec ? dWih : eWih) + (size_t)role * 3 * HID * HID;
        const float* Whh = (dec ? dWhh : eWhh) + (size_t)role * 3 * HID * HID;
        const float* bih = (dec ? dBih : eBih) + (size_t)role * 3 * HID;
        const float* bhh = (dec ? dBhh : eBhh) + (size_t)role * 3 * HID;
        u64* hch = dec ? (role ? D1 : D0) : (role ? H1 : H0);
        const u32 tagOut = dec ? (role ? 4u : 3u) : (role ? 2u : 1u);
        const float* xf = dec ? dec_x : enc_x;
        const u64* xt = dec ? D0 : H0;
        const u32 tagX = dec ? 3u : 1u;
        const u64* hinit = role ? (H1 + (size_t)(NSTEP - 1) * HID)
                                : (H0 + (size_t)(NSTEP - 1) * HID);
        const u32 tagInit = role ? 2u : 1u;

        __syncthreads();
#pragma unroll
        for (int r = 0; r < 12; ++r) {
            int R = wave * 12 + r;
            int m = (R < 24) ? R : R - 24;
            const float* base = ((R < 24) ? Wih : Whh) +
                                (size_t)((m >> 3) * HID + j0 + (m & 7)) * HID;
#pragma unroll
            for (int q = 0; q < 16; ++q) wreg[r][q] = base[q * 64 + lane];
        }
        if (tid < 48) {
            int m = (tid < 24) ? tid : tid - 24;
            sbias[tid] = ((tid < 24) ? bih : bhh)[(m >> 3) * HID + j0 + (m & 7)];
        }
        __syncthreads();

#pragma unroll 1
        for (int t = 0; t < NSTEP; ++t) {
            float v[16];
            if (wave < 2) {
                if (role == 0) {
                    const float* xr = xf + (size_t)t * HID;
#pragma unroll
                    for (int q = 0; q < 16; ++q) v[q] = xr[q * 64 + lane];
                } else {
                    poll16(xt + (size_t)t * HID, tagX, v, lane);
                }
            } else {
                if (t > 0) {
                    poll16(hch + (size_t)(t - 1) * HID, tagOut, v, lane);
                } else if (dec) {
                    poll16(hinit, tagInit, v, lane);
                } else {
#pragma unroll
                    for (int q = 0; q < 16; ++q) v[q] = 0.f;
                }
            }

            float part[12];
#pragma unroll
            for (int r = 0; r < 12; ++r) {
                float a = 0.f;
#pragma unroll
                for (int q = 0; q < 16; ++q) a = fmaf(wreg[r][q], v[q], a);
                part[r] = a;
            }
#pragma unroll
            for (int off = 1; off < 64; off <<= 1) {
#pragma unroll
                for (int r = 0; r < 12; ++r) part[r] += __shfl_xor(part[r], off);
            }
            if (lane == 0) {
#pragma unroll
                for (int r = 0; r < 12; ++r) dots[wave * 12 + r] = part[r];
            }
            __syncthreads();

            if (tid < 8) {
                const int jj = tid;
                float ir = dots[jj] + sbias[jj];
                float iz = dots[8 + jj] + sbias[8 + jj];
                float in_ = dots[16 + jj] + sbias[16 + jj];
                float hr = dots[24 + jj] + sbias[24 + jj];
                float hz = dots[32 + jj] + sbias[32 + jj];
                float hn = dots[40 + jj] + sbias[40 + jj];
                float rg = 1.f / (1.f + __expf(-(ir + hr)));
                float zg = 1.f / (1.f + __expf(-(iz + hz)));
                float na = in_ + rg * hn;
                float ng = 2.f / (1.f + __expf(-2.f * na)) - 1.f;  // tanh
                float hnew = (1.f - zg) * ng + zg * hprev;
                hprev = hnew;
                publish((u64*)(hch + (size_t)t * HID + j0 + jj),
                        pack_hv(hnew, tagOut));
                if (dec && role == 1) {
                    D1f[(size_t)t * HID + j0 + jj] = hnew;
                    D1b[(size_t)t * HID + j0 + jj] = (unsigned short)bf16_rtne(hnew);
                }
            }
            __syncthreads();
        }
    }
}

// ---------------------------------------------------------------- MFMA GEMM
// C[i][v] = sum_k A[i][k]*B[v][k] + bias[v]; A,B bf16 K-major; C f32.
// Block: 64 (M) x 256 (N); 4 waves; no LDS (B is L3-resident).
__global__ __launch_bounds__(256) void gemm_mfma(
    const unsigned short* __restrict__ A, const unsigned short* __restrict__ B,
    const float* __restrict__ bias, float* __restrict__ C) {
    typedef __attribute__((ext_vector_type(8))) short short8;
    typedef __attribute__((ext_vector_type(4))) float f32x4;
    const int lane = threadIdx.x & 63, wave = threadIdx.x >> 6;
    const int i0 = blockIdx.x * 64;
    const int v0 = blockIdx.y * 256 + wave * 64;
    const int r16 = lane & 15, kq = lane >> 4;

    f32x4 acc[4][4] = {};
#pragma unroll 4
    for (int k0 = 0; k0 < HID; k0 += 32) {
        short8 a[4], b[4];
#pragma unroll
        for (int mf = 0; mf < 4; ++mf)
            a[mf] = *(const short8*)(A + (size_t)(i0 + mf * 16 + r16) * HID + k0 +
                                     kq * 8);
#pragma unroll
        for (int nf = 0; nf < 4; ++nf)
            b[nf] = *(const short8*)(B + (size_t)(v0 + nf * 16 + r16) * HID + k0 +
                                     kq * 8);
#pragma unroll
        for (int mf = 0; mf < 4; ++mf)
#pragma unroll
            for (int nf = 0; nf < 4; ++nf)
                acc[mf][nf] = __builtin_amdgcn_mfma_f32_16x16x32_bf16(
                    a[mf], b[nf], acc[mf][nf], 0, 0, 0);
    }
#pragma unroll
    for (int nf = 0; nf < 4; ++nf) {
        float bb = bias[v0 + nf * 16 + r16];
#pragma unroll
        for (int mf = 0; mf < 4; ++mf)
#pragma unroll
            for (int reg = 0; reg < 4; ++reg) {
                int i = i0 + mf * 16 + kq * 4 + reg;
                C[(size_t)i * VOCAB + v0 + nf * 16 + r16] = acc[mf][nf][reg] + bb;
            }
    }
}

// ---------------------------------------------------------------- SIMT GEMM (fallback)
__global__ __launch_bounds__(256) void gemm_out(
    const float* __restrict__ A, const float* __restrict__ B,
    const float* __restrict__ bias, float* __restrict__ C, int ldc) {
    const int tid = threadIdx.x;
    const int bi = blockIdx.x;
    const int bv = blockIdx.y;
    const int i0 = bi * 64, v0 = bv * 128;
    __shared__ __align__(16) float As[32 * 68];
    __shared__ __align__(16) float Bs[32 * 132];
    const int tr = tid >> 4, tc = tid & 15;
    float c[4][8] = {};

    for (int kk = 0; kk < HID; kk += 32) {
#pragma unroll
        for (int q = 0; q < 2; q++) {
            int id = tid * 2 + q;
            int r = id >> 3, kq = id & 7;
            float4 a = *(const float4*)&A[(size_t)(i0 + r) * HID + kk + kq * 4];
            As[(kq * 4 + 0) * 68 + r] = a.x;
            As[(kq * 4 + 1) * 68 + r] = a.y;
            As[(kq * 4 + 2) * 68 + r] = a.z;
            As[(kq * 4 + 3) * 68 + r] = a.w;
        }
#pragma unroll
        for (int q = 0; q < 4; q++) {
            int id = tid * 4 + q;
            int vr = id >> 3, kq = id & 7;
            float4 b = *(const float4*)&B[(size_t)(v0 + vr) * HID + kk + kq * 4];
            Bs[(kq * 4 + 0) * 132 + vr] = b.x;
            Bs[(kq * 4 + 1) * 132 + vr] = b.y;
            Bs[(kq * 4 + 2) * 132 + vr] = b.z;
            Bs[(kq * 4 + 3) * 132 + vr] = b.w;
        }
        __syncthreads();
#pragma unroll
        for (int k = 0; k < 32; k++) {
            float4 a4 = *(const float4*)&As[k * 68 + tr * 4];
            float4 b0 = *(const float4*)&Bs[k * 132 + tc * 8];
            float4 b1 = *(const float4*)&Bs[k * 132 + tc * 8 + 4];
            float av[4] = {a4.x, a4.y, a4.z, a4.w};
            float bvv[8] = {b0.x, b0.y, b0.z, b0.w, b1.x, b1.y, b1.z, b1.w};
#pragma unroll
            for (int u = 0; u < 4; u++)
#pragma unroll
                for (int w = 0; w < 8; w++) c[u][w] += av[u] * bvv[w];
        }
        __syncthreads();
    }
    float4 bb0 = *(const float4*)&bias[v0 + tc * 8];
    float4 bb1 = *(const float4*)&bias[v0 + tc * 8 + 4];
#pragma unroll
    for (int u = 0; u < 4; u++) {
        int i = i0 + tr * 4 + u;
        float4 o0 = {c[u][0] + bb0.x, c[u][1] + bb0.y, c[u][2] + bb0.z, c[u][3] + bb0.w};
        float4 o1 = {c[u][4] + bb1.x, c[u][5] + bb1.y, c[u][6] + bb1.z, c[u][7] + bb1.w};
        *(float4*)&C[(size_t)i * ldc + v0 + tc * 8] = o0;
        *(float4*)&C[(size_t)i * ldc + v0 + tc * 8 + 4] = o1;
    }
}

// ---------------------------------------------------------------- log-softmax
__global__ __launch_bounds__(256) void log_softmax_inplace(float* __restrict__ C) {
    const int row = blockIdx.x;
    const int tid = threadIdx.x;
    float* p = C + (size_t)row * VOCAB;
    float m = -3.4e38f, s = 0.f;
    for (int idx = tid; idx < VOCAB / 4; idx += 256) {
        float4 x = ((const float4*)p)[idx];
        float xv[4] = {x.x, x.y, x.z, x.w};
#pragma unroll
        for (int u = 0; u < 4; u++) {
            float nm = fmaxf(m, xv[u]);
            s = s * __expf(m - nm) + __expf(xv[u] - nm);
            m = nm;
        }
    }
#pragma unroll
    for (int off = 1; off < 64; off <<= 1) {
        float om = __shfl_xor(m, off);
        float os = __shfl_xor(s, off);
        float nm = fmaxf(m, om);
        s = s * __expf(m - nm) + os * __expf(om - nm);
        m = nm;
    }
    __shared__ float sm[4], ss[4], sL;
    int wv = tid >> 6;
    if ((tid & 63) == 0) { sm[wv] = m; ss[wv] = s; }
    __syncthreads();
    if (tid == 0) {
        float M = sm[0], S = ss[0];
        for (int w = 1; w < 4; w++) {
            float nm = fmaxf(M, sm[w]);
            S = S * __expf(M - nm) + ss[w] * __expf(sm[w] - nm);
            M = nm;
        }
        sL = M + logf(S);
    }
    __syncthreads();
    float L = sL;
    for (int idx = tid; idx < VOCAB / 4; idx += 256) {
        float4 x = ((const float4*)p)[idx];
        x.x -= L; x.y -= L; x.z -= L; x.w -= L;
        ((float4*)p)[idx] = x;
    }
}

// ---------------------------------------------------------------- launcher
extern "C" void kernel_launch(void* const* d_in, const int* in_sizes, int n_in,
                              void* d_out, int out_size, void* d_ws, size_t ws_size,
                              hipStream_t stream) {
    const int* src_tok = (const int*)d_in[0];
    const int* tgt_tok = (const int*)d_in[1];
    const float* src_emb = (const float*)d_in[2];
    const float* tgt_emb = (const float*)d_in[3];
    const float* eWih = (const float*)d_in[4];
    const float* eWhh = (const float*)d_in[5];
    const float* eBih = (const float*)d_in[6];
    const float* eBhh = (const float*)d_in[7];
    const float* dWih = (const float*)d_in[8];
    const float* dWhh = (const float*)d_in[9];
    const float* dBih = (const float*)d_in[10];
    const float* dBhh = (const float*)d_in[11];
    const float* out_W = (const float*)d_in[12];
    const float* out_b = (const float*)d_in[13];
    float* out = (float*)d_out;

    char* ws = (char*)d_ws;
    // layout (MiB): enc_x 0-2 | dec_x 2-4 | H0 4-8 | H1 8-12 | D0 12-16 |
    //   D1 16-20 | D1f 20-22 | D1b 22-23 | Wb 23-87 (fast path only)
    float* enc_x = (float*)(ws);
    float* dec_x = (float*)(ws + (2ull << 20));
    u64* H0 = (u64*)(ws + (4ull << 20));
    u64* H1 = (u64*)(ws + (8ull << 20));
    u64* D0 = (u64*)(ws + (12ull << 20));
    u64* D1 = (u64*)(ws + (16ull << 20));
    float* D1f = (float*)(ws + (20ull << 20));
    unsigned short* D1b = (unsigned short*)(ws + (22ull << 20));
    unsigned short* Wb = (unsigned short*)(ws + (23ull << 20));
    const bool fast = ws_size >= (87ull << 20);

    // Clear sync tags every launch: stale/poisoned tags must never match.
    hipMemsetAsync(ws + (4ull << 20), 0, 16ull << 20, stream);

    gather_embed<<<1024, 256, 0, stream>>>(src_tok, tgt_tok, src_emb, tgt_emb,
                                           enc_x, dec_x);
    if (fast) cast_w<<<16000, 256, 0, stream>>>(out_W, Wb);

    gru_persist<<<256, 256, 0, stream>>>(enc_x, dec_x, eWih, eWhh, eBih, eBhh,
                                         dWih, dWhh, dBih, dBhh, H0, H1, D0, D1,
                                         D1f, D1b);

    if (fast)
        gemm_mfma<<<dim3(8, 125), 256, 0, stream>>>(D1b, Wb, out_b, out);
    else
        gemm_out<<<dim3(8, 250), 256, 0, stream>>>(D1f, out_W, out_b, out, VOCAB);
    log_softmax_inplace<<<512, 256, 0, stream>>>(out);
}